// Round 2
// baseline (427.163 us; speedup 1.0000x reference)
//
#include <hip/hip_runtime.h>
#include <hip/hip_bf16.h>
#include <math.h>

typedef __hip_bfloat16 bf16;
typedef __bf16 bf16x8 __attribute__((ext_vector_type(8)));
typedef float f32x4 __attribute__((ext_vector_type(4)));

static __device__ __forceinline__ float b2f(bf16 v) { return __bfloat162float(v); }
static __device__ __forceinline__ bf16 f2b(float v) { return __float2bfloat16(v); }

// ---------------------------------------------------------------------------
// Generic MFMA GEMM:  D[m][n] = sum_k A[m][k] * Bt[n][k]  (+ bias[m])
// A: M x K row-major bf16, Bt: N x K row-major bf16 (i.e. B^T), D: TOUT,
// natural or transposed store. Tile 128(M) x 64(N), BK=32. 256 thr = 4 waves.
// M % 128 == 0, N % 64 == 0, K % 32 == 0 (true for every call here).
// ---------------------------------------------------------------------------
#define TM 128
#define TN 64
#define TK 32

template <typename TOUT>
__global__ __launch_bounds__(256) void gemm_bt(
    const bf16* __restrict__ A, size_t sA,
    const bf16* __restrict__ Bt, size_t sB,
    const float* __restrict__ bias, size_t sBias, int hasBias,
    TOUT* __restrict__ D, size_t sD,
    int M, int N, int Kd, int transStore)
{
    A  += (size_t)blockIdx.z * sA;
    Bt += (size_t)blockIdx.z * sB;
    D  += (size_t)blockIdx.z * sD;
    if (hasBias) bias += (size_t)blockIdx.z * sBias;

    const int m0   = blockIdx.y * TM;
    const int n0   = blockIdx.x * TN;
    const int t    = threadIdx.x;
    const int wv   = t >> 6;
    const int lane = t & 63;
    const int lr   = lane & 15;
    const int quad = lane >> 4;

    __shared__ bf16 lA[TM][TK + 8];  // 80B row stride: 16B-aligned, conflict-spread
    __shared__ bf16 lB[TN][TK + 8];

    f32x4 acc[2][4];
#pragma unroll
    for (int i = 0; i < 2; ++i)
#pragma unroll
        for (int j = 0; j < 4; ++j)
            acc[i][j] = (f32x4){0.f, 0.f, 0.f, 0.f};

    // staging: A tile 128x32 = 16 elems/thread (two 16B), B tile 64x32 = 8/thread
    const int arow = t >> 1, acol = (t & 1) * 16;
    const int brow = t >> 2, bcol = (t & 3) * 8;
    const bf16* aptr = A  + (size_t)(m0 + arow) * Kd + acol;
    const bf16* bptr = Bt + (size_t)(n0 + brow) * Kd + bcol;

    for (int k0 = 0; k0 < Kd; k0 += TK) {
        __syncthreads();
        uint4 a0 = *(const uint4*)(aptr + k0);
        uint4 a1 = *(const uint4*)(aptr + k0 + 8);
        uint4 b0 = *(const uint4*)(bptr + k0);
        *(uint4*)(&lA[arow][acol])     = a0;
        *(uint4*)(&lA[arow][acol + 8]) = a1;
        *(uint4*)(&lB[brow][bcol])     = b0;
        __syncthreads();

        // A frag: A[m=lane&15][k=quad*8+j]; B frag: Bt[n=lane&15][k=quad*8+j]
        bf16x8 af0 = *(const bf16x8*)(&lA[wv * 32 + lr][quad * 8]);
        bf16x8 af1 = *(const bf16x8*)(&lA[wv * 32 + 16 + lr][quad * 8]);
#pragma unroll
        for (int j = 0; j < 4; ++j) {
            bf16x8 bfj = *(const bf16x8*)(&lB[j * 16 + lr][quad * 8]);
            acc[0][j] = __builtin_amdgcn_mfma_f32_16x16x32_bf16(af0, bfj, acc[0][j], 0, 0, 0);
            acc[1][j] = __builtin_amdgcn_mfma_f32_16x16x32_bf16(af1, bfj, acc[1][j], 0, 0, 0);
        }
    }

    // epilogue: C/D layout col(n) = lane&15, row(m) = quad*4 + reg
#pragma unroll
    for (int i = 0; i < 2; ++i) {
        const int mb = m0 + wv * 32 + i * 16 + quad * 4;
#pragma unroll
        for (int r = 0; r < 4; ++r) {
            const int mm = mb + r;
            const float bvv = hasBias ? bias[mm] : 0.f;
#pragma unroll
            for (int j = 0; j < 4; ++j) {
                const int nn = n0 + j * 16 + lr;
                const float v = acc[i][j][r] + bvv;
                const size_t o = transStore ? ((size_t)nn * M + mm)
                                            : ((size_t)mm * N + nn);
                if constexpr (__is_same(TOUT, float)) D[o] = v;
                else                                  D[o] = f2b(v);
            }
        }
    }
}

// ---------------------------------------------------------------------------
// Small kernels (all fp32 I/O)
// ---------------------------------------------------------------------------

__global__ void k_silu(const float* __restrict__ in, float* __restrict__ out, int n)
{
    int i = blockIdx.x * 256 + threadIdx.x;
    if (i < n) {
        float v = in[i];
        out[i] = v / (1.f + expf(-v));
    }
}

// xmean[b*512+c] = mean over HW of x[b][c][:]
__global__ void k_xmean(const float* __restrict__ x, float* __restrict__ xmean)
{
    const int bc = blockIdx.x;
    const float* p = x + (size_t)bc * 4096;
    float s = 0.f;
    for (int i = threadIdx.x; i < 4096; i += 256) s += p[i];
    for (int off = 32; off; off >>= 1) s += __shfl_down(s, off);
    __shared__ float red[4];
    if ((threadIdx.x & 63) == 0) red[threadIdx.x >> 6] = s;
    __syncthreads();
    if (threadIdx.x == 0)
        xmean[bc] = (red[0] + red[1] + red[2] + red[3]) * (1.f / 4096.f);
}

// out[m*O+o] = act( sum_k in[m*K+k] * W[o*K+k] + bias[o] ); one wave per output
__global__ void k_smallgemm(const float* __restrict__ in, const float* __restrict__ W,
                            const float* __restrict__ bias, float* __restrict__ out,
                            int Mrows, int O, int Kd, int act)
{
    const int gw = (blockIdx.x * 256 + threadIdx.x) >> 6;
    const int lane = threadIdx.x & 63;
    if (gw >= Mrows * O) return;
    const int m = gw / O, o = gw - m * O;
    float s = 0.f;
    for (int k = lane; k < Kd; k += 64)
        s += in[m * Kd + k] * W[(size_t)o * Kd + k];
    for (int off = 32; off; off >>= 1) s += __shfl_down(s, off);
    if (lane == 0) {
        s += bias[o];
        if (act) s = s / (1.f + expf(-s));
        out[m * O + o] = s;
    }
}

// hidden[m][o] = silu( sum_k pm[m][k]*w_m1[o][k] + b_m1[o] ),
// pm[k] = (1+scale)*xmean+shift (k<512)  |  tp[k-512]
__global__ void k_mlp1(const float* __restrict__ ss, const float* __restrict__ xmean,
                       const float* __restrict__ tp, const float* __restrict__ w_m1,
                       const float* __restrict__ b_m1, float* __restrict__ hidden)
{
    const int gw = (blockIdx.x * 256 + threadIdx.x) >> 6;  // 8192 waves
    const int lane = threadIdx.x & 63;
    if (gw >= 8 * 1024) return;
    const int m = gw >> 10, o = gw & 1023;
    float s = 0.f;
    for (int k = lane; k < 1024; k += 64) {
        float pv;
        if (k < 512) pv = (1.f + ss[m * 1024 + k]) * xmean[m * 512 + k] + ss[m * 1024 + 512 + k];
        else         pv = tp[m * 512 + k - 512];
        s += pv * w_m1[(size_t)o * 1024 + k];
    }
    for (int off = 32; off; off >>= 1) s += __shfl_down(s, off);
    if (lane == 0) {
        s += b_m1[o];
        hidden[m * 1024 + o] = s / (1.f + expf(-s));
    }
}

// top-256 of prompt[b][0..511]; set-equality suffices (order irrelevant downstream:
// a consistent permutation of q/k/v rows permutes attn rows+cols consistently and
// the wo-column gather undoes it). Rank tie-break by lower index = jax's SET.
__global__ void k_topk(const float* __restrict__ prompt, int* __restrict__ idx)
{
    __shared__ float v[512];
    __shared__ int sel[512];
    const int b = blockIdx.x, c = threadIdx.x;
    v[c] = prompt[b * 512 + c];
    __syncthreads();
    const float mv = v[c];
    int rank = 0;
    for (int j = 0; j < 512; ++j) {
        float o = v[j];
        rank += (o > mv) || (o == mv && j < c);
    }
    sel[c] = (rank < 256) ? 1 : 0;
    __syncthreads();
    if (rank < 256) {
        int pos = 0;
        for (int j = 0; j < c; ++j) pos += sel[j];
        idx[b * 256 + pos] = c;
    }
}

// hT[b][n][c] = bf16( x[b][c][n]*(1+scale[b][c]) + shift[b][c] ), 32x32 transpose
__global__ void k_hT(const float* __restrict__ x, const float* __restrict__ ss,
                     bf16* __restrict__ hT)
{
    __shared__ bf16 tile[32][33];
    const int b = blockIdx.z, c0 = blockIdx.y * 32, n0 = blockIdx.x * 32;
    const int t = threadIdx.x, tj = t & 31, ti = t >> 5;  // ti in 0..7
#pragma unroll
    for (int r = 0; r < 4; ++r) {
        const int i = ti + r * 8;           // c offset
        const int c = c0 + i;
        const float sc = 1.f + ss[b * 1024 + c];
        const float sh = ss[b * 1024 + 512 + c];
        const float xv = x[((size_t)b * 512 + c) * 4096 + n0 + tj];
        tile[i][tj] = f2b(xv * sc + sh);
    }
    __syncthreads();
#pragma unroll
    for (int r = 0; r < 4; ++r) {
        const int j = ti + r * 8;           // n offset
        hT[((size_t)b * 4096 + n0 + j) * 512 + c0 + tj] = tile[tj][j];
    }
}

// gather wq/wk/wv rows (fp32->bf16), biases (fp32), wo columns per top-k list
__global__ void k_gather(const int* __restrict__ idx,
                         const float* __restrict__ wq, const float* __restrict__ bq,
                         const float* __restrict__ wk, const float* __restrict__ bk,
                         const float* __restrict__ wv, const float* __restrict__ bv,
                         const float* __restrict__ wo,
                         bf16* __restrict__ wq_g, bf16* __restrict__ wk_g,
                         bf16* __restrict__ wv_g,
                         float* __restrict__ bq_g, float* __restrict__ bk_g,
                         float* __restrict__ bv_g, bf16* __restrict__ wo_g)
{
    const int b = blockIdx.z;
    const int* id = idx + b * 256;
    const int tid = blockIdx.x * 256 + threadIdx.x;  // 0..131071
    {
        const int j = tid >> 9, c = tid & 511;
        const int ch = id[j];
        const size_t o = (size_t)b * 131072 + tid;   // [b][j][c]
        wq_g[o] = f2b(wq[ch * 512 + c]);
        wk_g[o] = f2b(wk[ch * 512 + c]);
        wv_g[o] = f2b(wv[ch * 512 + c]);
    }
    {
        const int o = tid >> 8, j = tid & 255;       // [b][o][j]
        wo_g[(size_t)b * 131072 + tid] = f2b(wo[o * 512 + id[j]]);
    }
    if (tid < 256) {
        const int ch = id[tid];
        bq_g[b * 256 + tid] = bq[ch];
        bk_g[b * 256 + tid] = bk[ch];
        bv_g[b * 256 + tid] = bv[ch];
    }
}

// row softmax over 256 logits, scale = 1/sqrt(256) = 1/16 folded in
__global__ void k_softmax(const bf16* __restrict__ S, bf16* __restrict__ P)
{
    const int row = blockIdx.x;          // b*256 + j
    const int t = threadIdx.x;
    const int lane = t & 63, wv = t >> 6;
    __shared__ float redm[4], reds[4];
    const float v = b2f(S[(size_t)row * 256 + t]) * 0.0625f;
    float m = v;
    for (int off = 32; off; off >>= 1) m = fmaxf(m, __shfl_down(m, off));
    if (lane == 0) redm[wv] = m;
    __syncthreads();
    m = fmaxf(fmaxf(redm[0], redm[1]), fmaxf(redm[2], redm[3]));
    const float e = __expf(v - m);
    float s = e;
    for (int off = 32; off; off >>= 1) s += __shfl_down(s, off);
    if (lane == 0) reds[wv] = s;
    __syncthreads();
    s = reds[0] + reds[1] + reds[2] + reds[3];
    P[(size_t)row * 256 + t] = f2b(e / s);
}

// ---------------------------------------------------------------------------

extern "C" void kernel_launch(void* const* d_in, const int* in_sizes, int n_in,
                              void* d_out, int out_size, void* d_ws, size_t ws_size,
                              hipStream_t stream)
{
    const float* x        = (const float*)d_in[0];
    const float* temb     = (const float*)d_in[1];
    const float* w_affine = (const float*)d_in[2];
    const float* b_affine = (const float*)d_in[3];
    const float* w_tp     = (const float*)d_in[4];
    const float* b_tp     = (const float*)d_in[5];
    const float* w_m1     = (const float*)d_in[6];
    const float* b_m1     = (const float*)d_in[7];
    const float* w_m2     = (const float*)d_in[8];
    const float* b_m2     = (const float*)d_in[9];
    const float* wq       = (const float*)d_in[10];
    const float* bq       = (const float*)d_in[11];
    const float* wk       = (const float*)d_in[12];
    const float* bk       = (const float*)d_in[13];
    const float* wv       = (const float*)d_in[14];
    const float* bv       = (const float*)d_in[15];
    const float* wo       = (const float*)d_in[16];
    const float* bo       = (const float*)d_in[17];
    float* out = (float*)d_out;

    char* ws = (char*)d_ws;
    size_t off = 0;
    auto alloc = [&](size_t bytes) -> char* {
        char* p = ws + off;
        off += (bytes + 255) & ~(size_t)255;
        return p;
    };

    float* temb_act = (float*)alloc(4096 * 4);
    float* ssb      = (float*)alloc(8192 * 4);
    float* tp       = (float*)alloc(4096 * 4);
    float* xmean    = (float*)alloc(4096 * 4);
    float* hidden   = (float*)alloc(8192 * 4);
    float* prompt   = (float*)alloc(4096 * 4);
    int*   idx      = (int*)alloc(2048 * 4);
    bf16*  hT   = (bf16*)alloc((size_t)8 * 4096 * 512 * 2);
    bf16*  wq_g = (bf16*)alloc((size_t)8 * 256 * 512 * 2);
    bf16*  wk_g = (bf16*)alloc((size_t)8 * 256 * 512 * 2);
    bf16*  wv_g = (bf16*)alloc((size_t)8 * 256 * 512 * 2);
    float* bq_g = (float*)alloc(8 * 256 * 4);
    float* bk_g = (float*)alloc(8 * 256 * 4);
    float* bv_g = (float*)alloc(8 * 256 * 4);
    bf16*  wo_g = (bf16*)alloc((size_t)8 * 512 * 256 * 2);
    bf16*  qb   = (bf16*)alloc((size_t)8 * 256 * 4096 * 2);
    bf16*  kb   = (bf16*)alloc((size_t)8 * 256 * 4096 * 2);
    bf16*  vT   = (bf16*)alloc((size_t)8 * 4096 * 256 * 2);
    bf16*  Sb   = (bf16*)alloc((size_t)8 * 256 * 256 * 2);
    bf16*  Pb   = (bf16*)alloc((size_t)8 * 256 * 256 * 2);
    bf16*  outT = (bf16*)alloc((size_t)8 * 4096 * 256 * 2);
    (void)ws_size; (void)n_in; (void)in_sizes; (void)out_size;

    // 1) temb_act = silu(temb)
    k_silu<<<16, 256, 0, stream>>>(temb, temb_act, 4096);
    // 2) xmean (independent of everything else)
    k_xmean<<<4096, 256, 0, stream>>>(x, xmean);
    // 3) ss = temb_act @ w_affine^T + b_affine  (8x1024)
    k_smallgemm<<<2048, 256, 0, stream>>>(temb_act, w_affine, b_affine, ssb, 8, 1024, 512, 0);
    // 4) tp = temb_act @ w_tp^T + b_tp  (8x512)
    k_smallgemm<<<1024, 256, 0, stream>>>(temb_act, w_tp, b_tp, tp, 8, 512, 512, 0);
    // 5) hidden = silu(pm @ w_m1^T + b_m1)  (8x1024)
    k_mlp1<<<2048, 256, 0, stream>>>(ssb, xmean, tp, w_m1, b_m1, hidden);
    // 6) prompt = hidden @ w_m2^T + b_m2  (8x512)
    k_smallgemm<<<1024, 256, 0, stream>>>(hidden, w_m2, b_m2, prompt, 8, 512, 1024, 0);
    // 7) top-k indices (set, ascending)
    k_topk<<<8, 512, 0, stream>>>(prompt, idx);
    // 8) hT = transpose(h) with modulation applied, bf16
    k_hT<<<dim3(128, 16, 8), 256, 0, stream>>>(x, ssb, hT);
    // 9) gather weights/biases
    k_gather<<<dim3(512, 1, 8), 256, 0, stream>>>(idx, wq, bq, wk, bk, wv, bv, wo,
                                                  wq_g, wk_g, wv_g, bq_g, bk_g, bv_g, wo_g);
    // 10) QKV GEMMs: [256x512] @ [512x4096] per batch
    dim3 gQKV(64, 2, 8);
    gemm_bt<bf16><<<gQKV, 256, 0, stream>>>(wq_g, 131072, hT, 2097152, bq_g, 256, 1,
                                            qb, 1048576, 256, 4096, 512, 0);
    gemm_bt<bf16><<<gQKV, 256, 0, stream>>>(wk_g, 131072, hT, 2097152, bk_g, 256, 1,
                                            kb, 1048576, 256, 4096, 512, 0);
    gemm_bt<bf16><<<gQKV, 256, 0, stream>>>(wv_g, 131072, hT, 2097152, bv_g, 256, 1,
                                            vT, 1048576, 256, 4096, 512, 1);  // v^T
    // 11) S = q @ k^T  (256x256, K=4096)
    gemm_bt<bf16><<<dim3(4, 2, 8), 256, 0, stream>>>(qb, 1048576, kb, 1048576,
                                                     nullptr, 0, 0,
                                                     Sb, 65536, 256, 256, 4096, 0);
    // 12) P = softmax(S / 16)
    k_softmax<<<2048, 256, 0, stream>>>(Sb, Pb);
    // 13) outT = (P @ v)^T  (store transposed: [n][j])
    gemm_bt<bf16><<<dim3(64, 2, 8), 256, 0, stream>>>(Pb, 65536, vT, 1048576,
                                                      nullptr, 0, 0,
                                                      outT, 1048576, 256, 4096, 256, 1);
    // 14) out = wo_g @ outT^T + bo  (512x4096, fp32 out)
    gemm_bt<float><<<dim3(64, 4, 8), 256, 0, stream>>>(wo_g, 131072, outT, 1048576,
                                                       bo, 0, 1,
                                                       out, 2097152, 512, 4096, 256, 0);
}

// Round 3
// 407.889 us; speedup vs baseline: 1.0473x; 1.0473x over previous
//
#include <hip/hip_runtime.h>
#include <hip/hip_bf16.h>
#include <math.h>

typedef __hip_bfloat16 bf16;
typedef __bf16 bf16x8 __attribute__((ext_vector_type(8)));
typedef float f32x4 __attribute__((ext_vector_type(4)));

static __device__ __forceinline__ float b2f(bf16 v) { return __bfloat162float(v); }
static __device__ __forceinline__ bf16 f2b(float v) { return __float2bfloat16(v); }

// ---------------------------------------------------------------------------
// Generic MFMA GEMM:  D[m][n] = sum_k A[m][k] * Bt[n][k]  (+ bias[m])
// Tile 128(M) x 64(N), BK=32. 256 thr = 4 waves. M%128==0, N%64==0, K%32==0.
// ---------------------------------------------------------------------------
#define TM 128
#define TN 64
#define TK 32

template <typename TOUT>
__global__ __launch_bounds__(256) void gemm_bt(
    const bf16* __restrict__ A, size_t sA,
    const bf16* __restrict__ Bt, size_t sB,
    const float* __restrict__ bias, size_t sBias, int hasBias,
    TOUT* __restrict__ D, size_t sD,
    int M, int N, int Kd, int transStore)
{
    A  += (size_t)blockIdx.z * sA;
    Bt += (size_t)blockIdx.z * sB;
    D  += (size_t)blockIdx.z * sD;
    if (hasBias) bias += (size_t)blockIdx.z * sBias;

    const int m0 = blockIdx.y * TM, n0 = blockIdx.x * TN;
    const int t = threadIdx.x, wv = t >> 6, lane = t & 63;
    const int lr = lane & 15, quad = lane >> 4;

    __shared__ bf16 lA[TM][TK + 8];
    __shared__ bf16 lB[TN][TK + 8];

    f32x4 acc[2][4];
#pragma unroll
    for (int i = 0; i < 2; ++i)
#pragma unroll
        for (int j = 0; j < 4; ++j) acc[i][j] = (f32x4){0.f, 0.f, 0.f, 0.f};

    const int arow = t >> 1, acol = (t & 1) * 16;
    const int brow = t >> 2, bcol = (t & 3) * 8;
    const bf16* aptr = A  + (size_t)(m0 + arow) * Kd + acol;
    const bf16* bptr = Bt + (size_t)(n0 + brow) * Kd + bcol;

    for (int k0 = 0; k0 < Kd; k0 += TK) {
        __syncthreads();
        uint4 a0 = *(const uint4*)(aptr + k0);
        uint4 a1 = *(const uint4*)(aptr + k0 + 8);
        uint4 b0 = *(const uint4*)(bptr + k0);
        *(uint4*)(&lA[arow][acol])     = a0;
        *(uint4*)(&lA[arow][acol + 8]) = a1;
        *(uint4*)(&lB[brow][bcol])     = b0;
        __syncthreads();

        bf16x8 af0 = *(const bf16x8*)(&lA[wv * 32 + lr][quad * 8]);
        bf16x8 af1 = *(const bf16x8*)(&lA[wv * 32 + 16 + lr][quad * 8]);
#pragma unroll
        for (int j = 0; j < 4; ++j) {
            bf16x8 bfj = *(const bf16x8*)(&lB[j * 16 + lr][quad * 8]);
            acc[0][j] = __builtin_amdgcn_mfma_f32_16x16x32_bf16(af0, bfj, acc[0][j], 0, 0, 0);
            acc[1][j] = __builtin_amdgcn_mfma_f32_16x16x32_bf16(af1, bfj, acc[1][j], 0, 0, 0);
        }
    }

#pragma unroll
    for (int i = 0; i < 2; ++i) {
        const int mb = m0 + wv * 32 + i * 16 + quad * 4;
#pragma unroll
        for (int r = 0; r < 4; ++r) {
            const int mm = mb + r;
            const float bvv = hasBias ? bias[mm] : 0.f;
#pragma unroll
            for (int j = 0; j < 4; ++j) {
                const int nn = n0 + j * 16 + lr;
                const float v = acc[i][j][r] + bvv;
                const size_t o = transStore ? ((size_t)nn * M + mm)
                                            : ((size_t)mm * N + nn);
                if constexpr (__is_same(TOUT, float)) D[o] = v;
                else                                  D[o] = f2b(v);
            }
        }
    }
}

// ---------------------------------------------------------------------------
// Fused QKV GEMM: one hT B-tile staged per K-step feeds 3 stacked A-tiles.
// Aall: [b][3*256][512] (q rows 0-255, k 256-511, v 512-767). bias [b][768].
// q,k stored natural [b][256][4096]; v stored transposed [b][4096][256].
// Grid (64 n-tiles, 2 m-tiles, 8 batches).
// ---------------------------------------------------------------------------
__global__ __launch_bounds__(256) void gemm_qkv(
    const bf16* __restrict__ Aall, const bf16* __restrict__ hT,
    const float* __restrict__ bias,
    bf16* __restrict__ qb, bf16* __restrict__ kb, bf16* __restrict__ vT)
{
    const int b = blockIdx.z;
    const int m0 = blockIdx.y * 128;       // within each 256-row matrix
    const int n0 = blockIdx.x * 64;
    const bf16* A  = Aall + (size_t)b * 393216;
    const bf16* Bt = hT   + (size_t)b * 2097152;
    bias += b * 768;

    const int t = threadIdx.x, wv = t >> 6, lane = t & 63;
    const int lr = lane & 15, quad = lane >> 4;

    __shared__ bf16 lA[3][128][TK + 8];
    __shared__ bf16 lB[64][TK + 8];

    f32x4 acc[3][2][4];
#pragma unroll
    for (int m = 0; m < 3; ++m)
#pragma unroll
        for (int i = 0; i < 2; ++i)
#pragma unroll
            for (int j = 0; j < 4; ++j) acc[m][i][j] = (f32x4){0.f, 0.f, 0.f, 0.f};

    const int arow = t >> 1, acol = (t & 1) * 16;
    const int brow = t >> 2, bcol = (t & 3) * 8;
    const bf16* aptr = A  + (size_t)(m0 + arow) * 512 + acol;  // + mat*131072
    const bf16* bptr = Bt + (size_t)(n0 + brow) * 512 + bcol;

    for (int k0 = 0; k0 < 512; k0 += TK) {
        __syncthreads();
        uint4 a[3][2], b0;
#pragma unroll
        for (int m = 0; m < 3; ++m) {
            a[m][0] = *(const uint4*)(aptr + m * 131072 + k0);
            a[m][1] = *(const uint4*)(aptr + m * 131072 + k0 + 8);
        }
        b0 = *(const uint4*)(bptr + k0);
#pragma unroll
        for (int m = 0; m < 3; ++m) {
            *(uint4*)(&lA[m][arow][acol])     = a[m][0];
            *(uint4*)(&lA[m][arow][acol + 8]) = a[m][1];
        }
        *(uint4*)(&lB[brow][bcol]) = b0;
        __syncthreads();

        bf16x8 af[3][2];
#pragma unroll
        for (int m = 0; m < 3; ++m) {
            af[m][0] = *(const bf16x8*)(&lA[m][wv * 32 + lr][quad * 8]);
            af[m][1] = *(const bf16x8*)(&lA[m][wv * 32 + 16 + lr][quad * 8]);
        }
#pragma unroll
        for (int j = 0; j < 4; ++j) {
            bf16x8 bfj = *(const bf16x8*)(&lB[j * 16 + lr][quad * 8]);
#pragma unroll
            for (int m = 0; m < 3; ++m) {
                acc[m][0][j] = __builtin_amdgcn_mfma_f32_16x16x32_bf16(af[m][0], bfj, acc[m][0][j], 0, 0, 0);
                acc[m][1][j] = __builtin_amdgcn_mfma_f32_16x16x32_bf16(af[m][1], bfj, acc[m][1][j], 0, 0, 0);
            }
        }
    }

#pragma unroll
    for (int m = 0; m < 3; ++m) {
#pragma unroll
        for (int i = 0; i < 2; ++i) {
            const int mb = m0 + wv * 32 + i * 16 + quad * 4;
#pragma unroll
            for (int r = 0; r < 4; ++r) {
                const int mm = mb + r;
                const float bvv = bias[m * 256 + mm];
#pragma unroll
                for (int j = 0; j < 4; ++j) {
                    const int nn = n0 + j * 16 + lr;
                    const float v = acc[m][i][j][r] + bvv;
                    if (m == 0)      qb[(size_t)b * 1048576 + (size_t)mm * 4096 + nn] = f2b(v);
                    else if (m == 1) kb[(size_t)b * 1048576 + (size_t)mm * 4096 + nn] = f2b(v);
                    else             vT[(size_t)b * 1048576 + (size_t)nn * 256 + mm] = f2b(v);
                }
            }
        }
    }
}

// ---------------------------------------------------------------------------
// Split-K S-GEMM: part[s][b][m][n] = sum_{k in chunk s} q[b][m][k]*k[b][n][k]
// Grid (4 n-tiles, 2 m-tiles, 8*16), z = b*16+s. fp32 partials, no bias.
// ---------------------------------------------------------------------------
__global__ __launch_bounds__(256) void gemm_s_splitk(
    const bf16* __restrict__ qb, const bf16* __restrict__ kb,
    float* __restrict__ part)
{
    const int b = blockIdx.z >> 4, s = blockIdx.z & 15;
    const int m0 = blockIdx.y * TM, n0 = blockIdx.x * TN;
    const bf16* A  = qb + (size_t)b * 1048576;
    const bf16* Bt = kb + (size_t)b * 1048576;

    const int t = threadIdx.x, wv = t >> 6, lane = t & 63;
    const int lr = lane & 15, quad = lane >> 4;

    __shared__ bf16 lA[TM][TK + 8];
    __shared__ bf16 lB[TN][TK + 8];

    f32x4 acc[2][4];
#pragma unroll
    for (int i = 0; i < 2; ++i)
#pragma unroll
        for (int j = 0; j < 4; ++j) acc[i][j] = (f32x4){0.f, 0.f, 0.f, 0.f};

    const int arow = t >> 1, acol = (t & 1) * 16;
    const int brow = t >> 2, bcol = (t & 3) * 8;
    const bf16* aptr = A  + (size_t)(m0 + arow) * 4096 + acol;
    const bf16* bptr = Bt + (size_t)(n0 + brow) * 4096 + bcol;

    const int kBeg = s * 256, kEnd = kBeg + 256;
    for (int k0 = kBeg; k0 < kEnd; k0 += TK) {
        __syncthreads();
        uint4 a0 = *(const uint4*)(aptr + k0);
        uint4 a1 = *(const uint4*)(aptr + k0 + 8);
        uint4 b0 = *(const uint4*)(bptr + k0);
        *(uint4*)(&lA[arow][acol])     = a0;
        *(uint4*)(&lA[arow][acol + 8]) = a1;
        *(uint4*)(&lB[brow][bcol])     = b0;
        __syncthreads();

        bf16x8 af0 = *(const bf16x8*)(&lA[wv * 32 + lr][quad * 8]);
        bf16x8 af1 = *(const bf16x8*)(&lA[wv * 32 + 16 + lr][quad * 8]);
#pragma unroll
        for (int j = 0; j < 4; ++j) {
            bf16x8 bfj = *(const bf16x8*)(&lB[j * 16 + lr][quad * 8]);
            acc[0][j] = __builtin_amdgcn_mfma_f32_16x16x32_bf16(af0, bfj, acc[0][j], 0, 0, 0);
            acc[1][j] = __builtin_amdgcn_mfma_f32_16x16x32_bf16(af1, bfj, acc[1][j], 0, 0, 0);
        }
    }

    float* dst = part + ((size_t)(s * 8 + b) * 256) * 256;
#pragma unroll
    for (int i = 0; i < 2; ++i) {
        const int mb = m0 + wv * 32 + i * 16 + quad * 4;
#pragma unroll
        for (int r = 0; r < 4; ++r) {
            const int mm = mb + r;
#pragma unroll
            for (int j = 0; j < 4; ++j)
                dst[(size_t)mm * 256 + n0 + j * 16 + lr] = acc[i][j][r];
        }
    }
}

// ---------------------------------------------------------------------------
// Small kernels
// ---------------------------------------------------------------------------

__global__ void k_silu(const float* __restrict__ in, float* __restrict__ out, int n)
{
    int i = blockIdx.x * 256 + threadIdx.x;
    if (i < n) {
        float v = in[i];
        out[i] = v / (1.f + expf(-v));
    }
}

__global__ void k_smallgemm(const float* __restrict__ in, const float* __restrict__ W,
                            const float* __restrict__ bias, float* __restrict__ out,
                            int Mrows, int O, int Kd, int act)
{
    const int gw = (blockIdx.x * 256 + threadIdx.x) >> 6;
    const int lane = threadIdx.x & 63;
    if (gw >= Mrows * O) return;
    const int m = gw / O, o = gw - m * O;
    float s = 0.f;
    for (int k = lane; k < Kd; k += 64)
        s += in[m * Kd + k] * W[(size_t)o * Kd + k];
    for (int off = 32; off; off >>= 1) s += __shfl_down(s, off);
    if (lane == 0) {
        s += bias[o];
        if (act) s = s / (1.f + expf(-s));
        out[m * O + o] = s;
    }
}

// hidden[m][o] = silu(pm @ w_m1^T + b_m1); pm from ss/xsum(tot, /4096)/tp
__global__ void k_mlp1(const float* __restrict__ ss, const float* __restrict__ xsum,
                       const float* __restrict__ tp, const float* __restrict__ w_m1,
                       const float* __restrict__ b_m1, float* __restrict__ hidden)
{
    const int gw = (blockIdx.x * 256 + threadIdx.x) >> 6;
    const int lane = threadIdx.x & 63;
    if (gw >= 8 * 1024) return;
    const int m = gw >> 10, o = gw & 1023;
    float s = 0.f;
    for (int k = lane; k < 1024; k += 64) {
        float pv;
        if (k < 512) pv = (1.f + ss[m * 1024 + k]) * (xsum[m * 512 + k] * (1.f / 4096.f))
                          + ss[m * 1024 + 512 + k];
        else         pv = tp[m * 512 + k - 512];
        s += pv * w_m1[(size_t)o * 1024 + k];
    }
    for (int off = 32; off; off >>= 1) s += __shfl_down(s, off);
    if (lane == 0) {
        s += b_m1[o];
        hidden[m * 1024 + o] = s / (1.f + expf(-s));
    }
}

// top-256 set (order-free downstream; rank tie-break by lower index)
__global__ void k_topk(const float* __restrict__ prompt, int* __restrict__ idx)
{
    __shared__ float v[512];
    __shared__ int sel[512];
    const int b = blockIdx.x, c = threadIdx.x;
    v[c] = prompt[b * 512 + c];
    __syncthreads();
    const float mv = v[c];
    int rank = 0;
    for (int j = 0; j < 512; ++j) {
        float o = v[j];
        rank += (o > mv) || (o == mv && j < c);
    }
    sel[c] = (rank < 256) ? 1 : 0;
    __syncthreads();
    if (rank < 256) {
        int pos = 0;
        for (int j = 0; j < c; ++j) pos += sel[j];
        idx[b * 256 + pos] = c;
    }
}

// hT[b][n][c] = bf16(x*(1+scale)+shift), fused raw-x row-sum atomics into xsum
__global__ void k_hT(const float* __restrict__ x, const float* __restrict__ ss,
                     bf16* __restrict__ hT, float* __restrict__ xsum)
{
    __shared__ bf16 tile[32][33];
    const int b = blockIdx.z, c0 = blockIdx.y * 32, n0 = blockIdx.x * 32;
    const int t = threadIdx.x, tj = t & 31, ti = t >> 5;
    float rowsum[4];
#pragma unroll
    for (int r = 0; r < 4; ++r) {
        const int i = ti + r * 8;
        const int c = c0 + i;
        const float sc = 1.f + ss[b * 1024 + c];
        const float sh = ss[b * 1024 + 512 + c];
        const float xv = x[((size_t)b * 512 + c) * 4096 + n0 + tj];
        tile[i][tj] = f2b(xv * sc + sh);
        rowsum[r] = xv;
    }
#pragma unroll
    for (int r = 0; r < 4; ++r) {
        float s = rowsum[r];
        for (int off = 16; off; off >>= 1) s += __shfl_down(s, off, 32);
        if (tj == 0) atomicAdd(&xsum[b * 512 + c0 + ti + r * 8], s);
    }
    __syncthreads();
#pragma unroll
    for (int r = 0; r < 4; ++r) {
        const int j = ti + r * 8;
        hT[((size_t)b * 4096 + n0 + j) * 512 + c0 + tj] = tile[tj][j];
    }
}

// gather stacked wqkv rows, stacked biases, wo columns per top-k list
__global__ void k_gather(const int* __restrict__ idx,
                         const float* __restrict__ wq, const float* __restrict__ bq,
                         const float* __restrict__ wk, const float* __restrict__ bk,
                         const float* __restrict__ wv, const float* __restrict__ bv,
                         const float* __restrict__ wo,
                         bf16* __restrict__ wqkv_g, float* __restrict__ bqkv_g,
                         bf16* __restrict__ wo_g)
{
    const int b = blockIdx.z;
    const int* id = idx + b * 256;
    const int tid = blockIdx.x * 256 + threadIdx.x;  // < 393216
    {
        const int mat = tid >> 17, r = tid & 131071;
        const int j = r >> 9, c = r & 511;
        const int ch = id[j];
        const float* W = mat == 0 ? wq : (mat == 1 ? wk : wv);
        wqkv_g[(size_t)b * 393216 + tid] = f2b(W[ch * 512 + c]);
    }
    if (tid < 131072) {
        const int o = tid >> 8, j = tid & 255;
        wo_g[(size_t)b * 131072 + tid] = f2b(wo[o * 512 + id[j]]);
    }
    if (tid < 768) {
        const int m2 = tid >> 8, j = tid & 255;
        const float* Bv = m2 == 0 ? bq : (m2 == 1 ? bk : bv);
        bqkv_g[b * 768 + tid] = Bv[id[j]];
    }
}

// reduce 16 fp32 split-K partials, softmax row (scale 1/16), write P TRANSPOSED
__global__ void k_softmax_red(const float* __restrict__ part, bf16* __restrict__ Pt)
{
    const int row = blockIdx.x;          // b*256 + j
    const int b = row >> 8, j = row & 255;
    const int t = threadIdx.x;
    const int lane = t & 63, wv = t >> 6;
    __shared__ float redm[4], reds[4];
    float v = 0.f;
#pragma unroll
    for (int s = 0; s < 16; ++s)
        v += part[((size_t)(s * 8 + b) * 256 + j) * 256 + t];
    v *= 0.0625f;
    float m = v;
    for (int off = 32; off; off >>= 1) m = fmaxf(m, __shfl_down(m, off));
    if (lane == 0) redm[wv] = m;
    __syncthreads();
    m = fmaxf(fmaxf(redm[0], redm[1]), fmaxf(redm[2], redm[3]));
    const float e = __expf(v - m);
    float s = e;
    for (int off = 32; off; off >>= 1) s += __shfl_down(s, off);
    if (lane == 0) reds[wv] = s;
    __syncthreads();
    s = reds[0] + reds[1] + reds[2] + reds[3];
    Pt[(size_t)b * 65536 + (size_t)t * 256 + j] = f2b(e / s);  // P^T
}

// ---------------------------------------------------------------------------

extern "C" void kernel_launch(void* const* d_in, const int* in_sizes, int n_in,
                              void* d_out, int out_size, void* d_ws, size_t ws_size,
                              hipStream_t stream)
{
    const float* x        = (const float*)d_in[0];
    const float* temb     = (const float*)d_in[1];
    const float* w_affine = (const float*)d_in[2];
    const float* b_affine = (const float*)d_in[3];
    const float* w_tp     = (const float*)d_in[4];
    const float* b_tp     = (const float*)d_in[5];
    const float* w_m1     = (const float*)d_in[6];
    const float* b_m1     = (const float*)d_in[7];
    const float* w_m2     = (const float*)d_in[8];
    const float* b_m2     = (const float*)d_in[9];
    const float* wq       = (const float*)d_in[10];
    const float* bq       = (const float*)d_in[11];
    const float* wk       = (const float*)d_in[12];
    const float* bk       = (const float*)d_in[13];
    const float* wv       = (const float*)d_in[14];
    const float* bv       = (const float*)d_in[15];
    const float* wo       = (const float*)d_in[16];
    const float* bo       = (const float*)d_in[17];
    float* out = (float*)d_out;

    char* ws = (char*)d_ws;
    size_t off = 0;
    auto alloc = [&](size_t bytes) -> char* {
        char* p = ws + off;
        off += (bytes + 255) & ~(size_t)255;
        return p;
    };

    float* temb_act = (float*)alloc(4096 * 4);
    float* ssb      = (float*)alloc(8192 * 4);
    float* tp       = (float*)alloc(4096 * 4);
    float* xsum     = (float*)alloc(4096 * 4);
    float* hidden   = (float*)alloc(8192 * 4);
    float* prompt   = (float*)alloc(4096 * 4);
    int*   idx      = (int*)alloc(2048 * 4);
    // hT dead after QKV; part (same 33.5 MB) aliases it
    char*  hT_part  = alloc((size_t)8 * 4096 * 512 * 2);
    bf16*  hT   = (bf16*)hT_part;
    float* part = (float*)hT_part;                       // [16][8][256][256] fp32
    bf16*  wqkv_g = (bf16*)alloc((size_t)8 * 768 * 512 * 2);
    float* bqkv_g = (float*)alloc(8 * 768 * 4);
    bf16*  wo_g   = (bf16*)alloc((size_t)8 * 512 * 256 * 2);
    bf16*  qb     = (bf16*)alloc((size_t)8 * 256 * 4096 * 2);
    bf16*  kb     = (bf16*)alloc((size_t)8 * 256 * 4096 * 2);
    bf16*  vT     = (bf16*)alloc((size_t)8 * 4096 * 256 * 2);
    bf16*  Pt     = (bf16*)alloc((size_t)8 * 256 * 256 * 2);
    bf16*  W2     = (bf16*)alloc((size_t)8 * 512 * 256 * 2);
    (void)ws_size; (void)n_in; (void)in_sizes; (void)out_size;

    hipMemsetAsync(xsum, 0, 4096 * 4, stream);
    k_silu<<<16, 256, 0, stream>>>(temb, temb_act, 4096);
    k_smallgemm<<<2048, 256, 0, stream>>>(temb_act, w_affine, b_affine, ssb, 8, 1024, 512, 0);
    k_smallgemm<<<1024, 256, 0, stream>>>(temb_act, w_tp, b_tp, tp, 8, 512, 512, 0);
    // hT (+ xsum atomic accumulation)
    k_hT<<<dim3(128, 16, 8), 256, 0, stream>>>(x, ssb, hT, xsum);
    k_mlp1<<<2048, 256, 0, stream>>>(ssb, xsum, tp, w_m1, b_m1, hidden);
    k_smallgemm<<<1024, 256, 0, stream>>>(hidden, w_m2, b_m2, prompt, 8, 512, 1024, 0);
    k_topk<<<8, 512, 0, stream>>>(prompt, idx);
    k_gather<<<dim3(1536, 1, 8), 256, 0, stream>>>(idx, wq, bq, wk, bk, wv, bv, wo,
                                                   wqkv_g, bqkv_g, wo_g);
    // fused QKV: q,k natural; v transposed
    gemm_qkv<<<dim3(64, 2, 8), 256, 0, stream>>>(wqkv_g, hT, bqkv_g, qb, kb, vT);
    // S split-K (part aliases hT, which is dead now)
    gemm_s_splitk<<<dim3(4, 2, 128), 256, 0, stream>>>(qb, kb, part);
    // softmax + split reduction -> P^T
    k_softmax_red<<<2048, 256, 0, stream>>>(part, Pt);
    // W2 = wo_g @ P  (512x256, K=256):  W2[m][l] = sum_j wo_g[m][j] * Pt[l][j]
    gemm_bt<bf16><<<dim3(4, 4, 8), 256, 0, stream>>>(wo_g, 131072, Pt, 65536,
                                                     nullptr, 0, 0,
                                                     W2, 131072, 512, 256, 256, 0);
    // out = W2 @ v + bo  (512x4096, K=256): out[m][n] = sum_l W2[m][l]*vT[n][l]
    gemm_bt<float><<<dim3(64, 4, 8), 256, 0, stream>>>(W2, 131072, vT, 1048576,
                                                       bo, 0, 1,
                                                       out, 2097152, 512, 4096, 256, 0);
}

// Round 4
// 333.272 us; speedup vs baseline: 1.2817x; 1.2239x over previous
//
#include <hip/hip_runtime.h>
#include <hip/hip_bf16.h>
#include <math.h>

typedef __hip_bfloat16 bf16;
typedef __bf16 bf16x8 __attribute__((ext_vector_type(8)));
typedef float f32x4 __attribute__((ext_vector_type(4)));

static __device__ __forceinline__ float b2f(bf16 v) { return __bfloat162float(v); }
static __device__ __forceinline__ bf16 f2b(float v) { return __float2bfloat16(v); }

// ---------------------------------------------------------------------------
// Generic MFMA GEMM:  D[m][n] = sum_k A[m][k] * Bt[n][k]  (+ bias[m])
// Tile 128(M) x 64(N), BK=32. 256 thr = 4 waves. M%128==0, N%64==0, K%32==0.
// ---------------------------------------------------------------------------
#define TM 128
#define TN 64
#define TK 32

template <typename TOUT>
__global__ __launch_bounds__(256) void gemm_bt(
    const bf16* __restrict__ A, size_t sA,
    const bf16* __restrict__ Bt, size_t sB,
    const float* __restrict__ bias, size_t sBias, int hasBias,
    TOUT* __restrict__ D, size_t sD,
    int M, int N, int Kd, int transStore)
{
    A  += (size_t)blockIdx.z * sA;
    Bt += (size_t)blockIdx.z * sB;
    D  += (size_t)blockIdx.z * sD;
    if (hasBias) bias += (size_t)blockIdx.z * sBias;

    const int m0 = blockIdx.y * TM, n0 = blockIdx.x * TN;
    const int t = threadIdx.x, wv = t >> 6, lane = t & 63;
    const int lr = lane & 15, quad = lane >> 4;

    __shared__ bf16 lA[TM][TK + 8];
    __shared__ bf16 lB[TN][TK + 8];

    f32x4 acc[2][4];
#pragma unroll
    for (int i = 0; i < 2; ++i)
#pragma unroll
        for (int j = 0; j < 4; ++j) acc[i][j] = (f32x4){0.f, 0.f, 0.f, 0.f};

    const int arow = t >> 1, acol = (t & 1) * 16;
    const int brow = t >> 2, bcol = (t & 3) * 8;
    const bf16* aptr = A  + (size_t)(m0 + arow) * Kd + acol;
    const bf16* bptr = Bt + (size_t)(n0 + brow) * Kd + bcol;

    for (int k0 = 0; k0 < Kd; k0 += TK) {
        __syncthreads();
        uint4 a0 = *(const uint4*)(aptr + k0);
        uint4 a1 = *(const uint4*)(aptr + k0 + 8);
        uint4 b0 = *(const uint4*)(bptr + k0);
        *(uint4*)(&lA[arow][acol])     = a0;
        *(uint4*)(&lA[arow][acol + 8]) = a1;
        *(uint4*)(&lB[brow][bcol])     = b0;
        __syncthreads();

        bf16x8 af0 = *(const bf16x8*)(&lA[wv * 32 + lr][quad * 8]);
        bf16x8 af1 = *(const bf16x8*)(&lA[wv * 32 + 16 + lr][quad * 8]);
#pragma unroll
        for (int j = 0; j < 4; ++j) {
            bf16x8 bfj = *(const bf16x8*)(&lB[j * 16 + lr][quad * 8]);
            acc[0][j] = __builtin_amdgcn_mfma_f32_16x16x32_bf16(af0, bfj, acc[0][j], 0, 0, 0);
            acc[1][j] = __builtin_amdgcn_mfma_f32_16x16x32_bf16(af1, bfj, acc[1][j], 0, 0, 0);
        }
    }

#pragma unroll
    for (int i = 0; i < 2; ++i) {
        const int mb = m0 + wv * 32 + i * 16 + quad * 4;
#pragma unroll
        for (int r = 0; r < 4; ++r) {
            const int mm = mb + r;
            const float bvv = hasBias ? bias[mm] : 0.f;
#pragma unroll
            for (int j = 0; j < 4; ++j) {
                const int nn = n0 + j * 16 + lr;
                const float v = acc[i][j][r] + bvv;
                const size_t o = transStore ? ((size_t)nn * M + mm)
                                            : ((size_t)mm * N + nn);
                if constexpr (__is_same(TOUT, float)) D[o] = v;
                else                                  D[o] = f2b(v);
            }
        }
    }
}

// ---------------------------------------------------------------------------
// Fused QKV GEMM reading x DIRECTLY (no hT intermediate).
// B-tile staged from x[b][c][n] natural layout with coalesced float4 loads,
// modulation (1+scale_c)*x+shift_c applied in registers, transposed into LDS
// with XOR-swizzled 8-elem k-groups (conflict-free writes AND b128 reads).
// Aall: [b][3*256][512] stacked gathered wq/wk/wv (bf16). bias [b][768].
// q,k stored natural [b][256][4096]; v stored transposed [b][4096][256].
// Grid (64 n-tiles, 2 m-tiles, 8 batches).
// ---------------------------------------------------------------------------
#define BROW 40   // padded LDS row stride for B tile (80 B)

__global__ __launch_bounds__(256) void gemm_qkv(
    const bf16* __restrict__ Aall, const float* __restrict__ x,
    const float* __restrict__ ss, const float* __restrict__ bias,
    bf16* __restrict__ qb, bf16* __restrict__ kb, bf16* __restrict__ vT)
{
    const int b = blockIdx.z;
    const int m0 = blockIdx.y * 128;
    const int n0 = blockIdx.x * 64;
    const bf16* A = Aall + (size_t)b * 393216;
    bias += b * 768;

    const int t = threadIdx.x, wv = t >> 6, lane = t & 63;
    const int lr = lane & 15, quad = lane >> 4;

    __shared__ bf16 lA[3][128][TK + 8];
    __shared__ bf16 lBf[64 * BROW];

    f32x4 acc[3][2][4];
#pragma unroll
    for (int m = 0; m < 3; ++m)
#pragma unroll
        for (int i = 0; i < 2; ++i)
#pragma unroll
            for (int j = 0; j < 4; ++j) acc[m][i][j] = (f32x4){0.f, 0.f, 0.f, 0.f};

    // A staging: 128x32 per matrix, 16 elems/thread
    const int arow = t >> 1, acol = (t & 1) * 16;
    const bf16* aptr = A + (size_t)(m0 + arow) * 512 + acol;  // + mat*131072
    // B staging: thread covers k-row kk (in-tile), 8 n's starting at nc
    const int kk = t >> 3;          // 0..31
    const int w8 = kk >> 3;         // k-group 0..3 (== wave id)
    const int nc = (t & 7) * 8;
    const float* xp0 = x + ((size_t)b * 512 + kk) * 4096 + n0 + nc;
    const float* ssp = ss + b * 1024 + kk;

    for (int k0 = 0; k0 < 512; k0 += TK) {
        __syncthreads();
        uint4 a[3][2];
#pragma unroll
        for (int m = 0; m < 3; ++m) {
            a[m][0] = *(const uint4*)(aptr + m * 131072 + k0);
            a[m][1] = *(const uint4*)(aptr + m * 131072 + k0 + 8);
        }
        const float4 f0 = *(const float4*)(xp0 + (size_t)k0 * 4096);
        const float4 f1 = *(const float4*)(xp0 + (size_t)k0 * 4096 + 4);
        const float sc = 1.f + ssp[k0];
        const float sh = ssp[512 + k0];
#pragma unroll
        for (int m = 0; m < 3; ++m) {
            *(uint4*)(&lA[m][arow][acol])     = a[m][0];
            *(uint4*)(&lA[m][arow][acol + 8]) = a[m][1];
        }
        {
            const float vals[8] = {f0.x, f0.y, f0.z, f0.w, f1.x, f1.y, f1.z, f1.w};
#pragma unroll
            for (int i = 0; i < 8; ++i) {
                const int n = nc + i;
                lBf[n * BROW + ((w8 ^ ((n >> 3) & 3)) << 3) + (kk & 7)] =
                    f2b(fmaf(vals[i], sc, sh));
            }
        }
        __syncthreads();

        bf16x8 af[3][2];
#pragma unroll
        for (int m = 0; m < 3; ++m) {
            af[m][0] = *(const bf16x8*)(&lA[m][wv * 32 + lr][quad * 8]);
            af[m][1] = *(const bf16x8*)(&lA[m][wv * 32 + 16 + lr][quad * 8]);
        }
#pragma unroll
        for (int j = 0; j < 4; ++j) {
            const int n = j * 16 + lr;
            bf16x8 bfj = *(const bf16x8*)(&lBf[n * BROW + ((quad ^ ((n >> 3) & 3)) << 3)]);
#pragma unroll
            for (int m = 0; m < 3; ++m) {
                acc[m][0][j] = __builtin_amdgcn_mfma_f32_16x16x32_bf16(af[m][0], bfj, acc[m][0][j], 0, 0, 0);
                acc[m][1][j] = __builtin_amdgcn_mfma_f32_16x16x32_bf16(af[m][1], bfj, acc[m][1][j], 0, 0, 0);
            }
        }
    }

#pragma unroll
    for (int m = 0; m < 3; ++m) {
#pragma unroll
        for (int i = 0; i < 2; ++i) {
            const int mb = m0 + wv * 32 + i * 16 + quad * 4;
#pragma unroll
            for (int r = 0; r < 4; ++r) {
                const int mm = mb + r;
                const float bvv = bias[m * 256 + mm];
#pragma unroll
                for (int j = 0; j < 4; ++j) {
                    const int nn = n0 + j * 16 + lr;
                    const float v = acc[m][i][j][r] + bvv;
                    if (m == 0)      qb[(size_t)b * 1048576 + (size_t)mm * 4096 + nn] = f2b(v);
                    else if (m == 1) kb[(size_t)b * 1048576 + (size_t)mm * 4096 + nn] = f2b(v);
                    else             vT[(size_t)b * 1048576 + (size_t)nn * 256 + mm] = f2b(v);
                }
            }
        }
    }
}

// ---------------------------------------------------------------------------
// Split-K S-GEMM: part[s][b][m][n] = sum_{k in chunk s} q[b][m][k]*k[b][n][k]
// ---------------------------------------------------------------------------
__global__ __launch_bounds__(256) void gemm_s_splitk(
    const bf16* __restrict__ qb, const bf16* __restrict__ kb,
    float* __restrict__ part)
{
    const int b = blockIdx.z >> 4, s = blockIdx.z & 15;
    const int m0 = blockIdx.y * TM, n0 = blockIdx.x * TN;
    const bf16* A  = qb + (size_t)b * 1048576;
    const bf16* Bt = kb + (size_t)b * 1048576;

    const int t = threadIdx.x, wv = t >> 6, lane = t & 63;
    const int lr = lane & 15, quad = lane >> 4;

    __shared__ bf16 lA[TM][TK + 8];
    __shared__ bf16 lB[TN][TK + 8];

    f32x4 acc[2][4];
#pragma unroll
    for (int i = 0; i < 2; ++i)
#pragma unroll
        for (int j = 0; j < 4; ++j) acc[i][j] = (f32x4){0.f, 0.f, 0.f, 0.f};

    const int arow = t >> 1, acol = (t & 1) * 16;
    const int brow = t >> 2, bcol = (t & 3) * 8;
    const bf16* aptr = A  + (size_t)(m0 + arow) * 4096 + acol;
    const bf16* bptr = Bt + (size_t)(n0 + brow) * 4096 + bcol;

    const int kBeg = s * 256, kEnd = kBeg + 256;
    for (int k0 = kBeg; k0 < kEnd; k0 += TK) {
        __syncthreads();
        uint4 a0 = *(const uint4*)(aptr + k0);
        uint4 a1 = *(const uint4*)(aptr + k0 + 8);
        uint4 b0 = *(const uint4*)(bptr + k0);
        *(uint4*)(&lA[arow][acol])     = a0;
        *(uint4*)(&lA[arow][acol + 8]) = a1;
        *(uint4*)(&lB[brow][bcol])     = b0;
        __syncthreads();

        bf16x8 af0 = *(const bf16x8*)(&lA[wv * 32 + lr][quad * 8]);
        bf16x8 af1 = *(const bf16x8*)(&lA[wv * 32 + 16 + lr][quad * 8]);
#pragma unroll
        for (int j = 0; j < 4; ++j) {
            bf16x8 bfj = *(const bf16x8*)(&lB[j * 16 + lr][quad * 8]);
            acc[0][j] = __builtin_amdgcn_mfma_f32_16x16x32_bf16(af0, bfj, acc[0][j], 0, 0, 0);
            acc[1][j] = __builtin_amdgcn_mfma_f32_16x16x32_bf16(af1, bfj, acc[1][j], 0, 0, 0);
        }
    }

    float* dst = part + ((size_t)(s * 8 + b) * 256) * 256;
#pragma unroll
    for (int i = 0; i < 2; ++i) {
        const int mb = m0 + wv * 32 + i * 16 + quad * 4;
#pragma unroll
        for (int r = 0; r < 4; ++r) {
            const int mm = mb + r;
#pragma unroll
            for (int j = 0; j < 4; ++j)
                dst[(size_t)mm * 256 + n0 + j * 16 + lr] = acc[i][j][r];
        }
    }
}

// ---------------------------------------------------------------------------
// Small kernels
// ---------------------------------------------------------------------------

__global__ void k_silu(const float* __restrict__ in, float* __restrict__ out, int n)
{
    int i = blockIdx.x * 256 + threadIdx.x;
    if (i < n) {
        float v = in[i];
        out[i] = v / (1.f + expf(-v));
    }
}

// xsum[bc] = sum over HW of x[bc][:], float4 streaming
__global__ void k_xmean(const float* __restrict__ x, float* __restrict__ xsum)
{
    const int bc = blockIdx.x;
    const float4* p = (const float4*)(x + (size_t)bc * 4096);
    float s = 0.f;
#pragma unroll
    for (int r = 0; r < 4; ++r) {
        float4 v = p[threadIdx.x + r * 256];
        s += v.x + v.y + v.z + v.w;
    }
    for (int off = 32; off; off >>= 1) s += __shfl_down(s, off);
    __shared__ float red[4];
    if ((threadIdx.x & 63) == 0) red[threadIdx.x >> 6] = s;
    __syncthreads();
    if (threadIdx.x == 0)
        xsum[bc] = red[0] + red[1] + red[2] + red[3];
}

__global__ void k_smallgemm(const float* __restrict__ in, const float* __restrict__ W,
                            const float* __restrict__ bias, float* __restrict__ out,
                            int Mrows, int O, int Kd, int act)
{
    const int gw = (blockIdx.x * 256 + threadIdx.x) >> 6;
    const int lane = threadIdx.x & 63;
    if (gw >= Mrows * O) return;
    const int m = gw / O, o = gw - m * O;
    float s = 0.f;
    for (int k = lane; k < Kd; k += 64)
        s += in[m * Kd + k] * W[(size_t)o * Kd + k];
    for (int off = 32; off; off >>= 1) s += __shfl_down(s, off);
    if (lane == 0) {
        s += bias[o];
        if (act) s = s / (1.f + expf(-s));
        out[m * O + o] = s;
    }
}

// hidden[m][o] = silu(pm @ w_m1^T + b_m1); pm from ss/xsum(total, /4096)/tp
__global__ void k_mlp1(const float* __restrict__ ss, const float* __restrict__ xsum,
                       const float* __restrict__ tp, const float* __restrict__ w_m1,
                       const float* __restrict__ b_m1, float* __restrict__ hidden)
{
    const int gw = (blockIdx.x * 256 + threadIdx.x) >> 6;
    const int lane = threadIdx.x & 63;
    if (gw >= 8 * 1024) return;
    const int m = gw >> 10, o = gw & 1023;
    float s = 0.f;
    for (int k = lane; k < 1024; k += 64) {
        float pv;
        if (k < 512) pv = (1.f + ss[m * 1024 + k]) * (xsum[m * 512 + k] * (1.f / 4096.f))
                          + ss[m * 1024 + 512 + k];
        else         pv = tp[m * 512 + k - 512];
        s += pv * w_m1[(size_t)o * 1024 + k];
    }
    for (int off = 32; off; off >>= 1) s += __shfl_down(s, off);
    if (lane == 0) {
        s += b_m1[o];
        hidden[m * 1024 + o] = s / (1.f + expf(-s));
    }
}

// top-256 set (order-free downstream; rank tie-break by lower index)
__global__ void k_topk(const float* __restrict__ prompt, int* __restrict__ idx)
{
    __shared__ float v[512];
    __shared__ int sel[512];
    const int b = blockIdx.x, c = threadIdx.x;
    v[c] = prompt[b * 512 + c];
    __syncthreads();
    const float mv = v[c];
    int rank = 0;
    for (int j = 0; j < 512; ++j) {
        float o = v[j];
        rank += (o > mv) || (o == mv && j < c);
    }
    sel[c] = (rank < 256) ? 1 : 0;
    __syncthreads();
    if (rank < 256) {
        int pos = 0;
        for (int j = 0; j < c; ++j) pos += sel[j];
        idx[b * 256 + pos] = c;
    }
}

// gather stacked wqkv rows, stacked biases, wo columns per top-k list
__global__ void k_gather(const int* __restrict__ idx,
                         const float* __restrict__ wq, const float* __restrict__ bq,
                         const float* __restrict__ wk, const float* __restrict__ bk,
                         const float* __restrict__ wv, const float* __restrict__ bv,
                         const float* __restrict__ wo,
                         bf16* __restrict__ wqkv_g, float* __restrict__ bqkv_g,
                         bf16* __restrict__ wo_g)
{
    const int b = blockIdx.z;
    const int* id = idx + b * 256;
    const int tid = blockIdx.x * 256 + threadIdx.x;  // < 393216
    {
        const int mat = tid >> 17, r = tid & 131071;
        const int j = r >> 9, c = r & 511;
        const int ch = id[j];
        const float* W = mat == 0 ? wq : (mat == 1 ? wk : wv);
        wqkv_g[(size_t)b * 393216 + tid] = f2b(W[ch * 512 + c]);
    }
    if (tid < 131072) {
        const int o = tid >> 8, j = tid & 255;
        wo_g[(size_t)b * 131072 + tid] = f2b(wo[o * 512 + id[j]]);
    }
    if (tid < 768) {
        const int m2 = tid >> 8, j = tid & 255;
        const float* Bv = m2 == 0 ? bq : (m2 == 1 ? bk : bv);
        bqkv_g[b * 768 + tid] = Bv[id[j]];
    }
}

// reduce 16 fp32 split-K partials, softmax row (scale 1/16), write P TRANSPOSED
__global__ void k_softmax_red(const float* __restrict__ part, bf16* __restrict__ Pt)
{
    const int row = blockIdx.x;          // b*256 + j
    const int b = row >> 8, j = row & 255;
    const int t = threadIdx.x;
    const int lane = t & 63, wv = t >> 6;
    __shared__ float redm[4], reds[4];
    float v = 0.f;
#pragma unroll
    for (int s = 0; s < 16; ++s)
        v += part[((size_t)(s * 8 + b) * 256 + j) * 256 + t];
    v *= 0.0625f;
    float m = v;
    for (int off = 32; off; off >>= 1) m = fmaxf(m, __shfl_down(m, off));
    if (lane == 0) redm[wv] = m;
    __syncthreads();
    m = fmaxf(fmaxf(redm[0], redm[1]), fmaxf(redm[2], redm[3]));
    const float e = __expf(v - m);
    float s = e;
    for (int off = 32; off; off >>= 1) s += __shfl_down(s, off);
    if (lane == 0) reds[wv] = s;
    __syncthreads();
    s = reds[0] + reds[1] + reds[2] + reds[3];
    Pt[(size_t)b * 65536 + (size_t)t * 256 + j] = f2b(e / s);  // P^T
}

// ---------------------------------------------------------------------------

extern "C" void kernel_launch(void* const* d_in, const int* in_sizes, int n_in,
                              void* d_out, int out_size, void* d_ws, size_t ws_size,
                              hipStream_t stream)
{
    const float* x        = (const float*)d_in[0];
    const float* temb     = (const float*)d_in[1];
    const float* w_affine = (const float*)d_in[2];
    const float* b_affine = (const float*)d_in[3];
    const float* w_tp     = (const float*)d_in[4];
    const float* b_tp     = (const float*)d_in[5];
    const float* w_m1     = (const float*)d_in[6];
    const float* b_m1     = (const float*)d_in[7];
    const float* w_m2     = (const float*)d_in[8];
    const float* b_m2     = (const float*)d_in[9];
    const float* wq       = (const float*)d_in[10];
    const float* bq       = (const float*)d_in[11];
    const float* wk       = (const float*)d_in[12];
    const float* bk       = (const float*)d_in[13];
    const float* wv       = (const float*)d_in[14];
    const float* bv       = (const float*)d_in[15];
    const float* wo       = (const float*)d_in[16];
    const float* bo       = (const float*)d_in[17];
    float* out = (float*)d_out;

    char* ws = (char*)d_ws;
    size_t off = 0;
    auto alloc = [&](size_t bytes) -> char* {
        char* p = ws + off;
        off += (bytes + 255) & ~(size_t)255;
        return p;
    };

    float* temb_act = (float*)alloc(4096 * 4);
    float* ssb      = (float*)alloc(8192 * 4);
    float* tp       = (float*)alloc(4096 * 4);
    float* xsum     = (float*)alloc(4096 * 4);
    float* hidden   = (float*)alloc(8192 * 4);
    float* prompt   = (float*)alloc(4096 * 4);
    int*   idx      = (int*)alloc(2048 * 4);
    float* part   = (float*)alloc((size_t)16 * 8 * 256 * 256 * 4);  // split-K partials
    bf16*  wqkv_g = (bf16*)alloc((size_t)8 * 768 * 512 * 2);
    float* bqkv_g = (float*)alloc(8 * 768 * 4);
    bf16*  wo_g   = (bf16*)alloc((size_t)8 * 512 * 256 * 2);
    bf16*  qb     = (bf16*)alloc((size_t)8 * 256 * 4096 * 2);
    bf16*  kb     = (bf16*)alloc((size_t)8 * 256 * 4096 * 2);
    bf16*  vT     = (bf16*)alloc((size_t)8 * 4096 * 256 * 2);
    bf16*  Pt     = (bf16*)alloc((size_t)8 * 256 * 256 * 2);
    bf16*  W2     = (bf16*)alloc((size_t)8 * 512 * 256 * 2);
    (void)ws_size; (void)n_in; (void)in_sizes; (void)out_size;

    k_silu<<<16, 256, 0, stream>>>(temb, temb_act, 4096);
    k_xmean<<<4096, 256, 0, stream>>>(x, xsum);
    k_smallgemm<<<2048, 256, 0, stream>>>(temb_act, w_affine, b_affine, ssb, 8, 1024, 512, 0);
    k_smallgemm<<<1024, 256, 0, stream>>>(temb_act, w_tp, b_tp, tp, 8, 512, 512, 0);
    k_mlp1<<<2048, 256, 0, stream>>>(ssb, xsum, tp, w_m1, b_m1, hidden);
    k_smallgemm<<<1024, 256, 0, stream>>>(hidden, w_m2, b_m2, prompt, 8, 512, 1024, 0);
    k_topk<<<8, 512, 0, stream>>>(prompt, idx);
    k_gather<<<dim3(1536, 1, 8), 256, 0, stream>>>(idx, wq, bq, wk, bk, wv, bv, wo,
                                                   wqkv_g, bqkv_g, wo_g);
    // fused QKV straight from x (modulation fused into B staging)
    gemm_qkv<<<dim3(64, 2, 8), 256, 0, stream>>>(wqkv_g, x, ssb, bqkv_g, qb, kb, vT);
    // S split-K
    gemm_s_splitk<<<dim3(4, 2, 128), 256, 0, stream>>>(qb, kb, part);
    // softmax + split reduction -> P^T
    k_softmax_red<<<2048, 256, 0, stream>>>(part, Pt);
    // W2 = wo_g @ P  (512x256, K=256)
    gemm_bt<bf16><<<dim3(4, 4, 8), 256, 0, stream>>>(wo_g, 131072, Pt, 65536,
                                                     nullptr, 0, 0,
                                                     W2, 131072, 512, 256, 256, 0);
    // out = W2 @ v + bo  (512x4096, K=256)
    gemm_bt<float><<<dim3(64, 4, 8), 256, 0, stream>>>(W2, 131072, vT, 1048576,
                                                       bo, 0, 1,
                                                       out, 2097152, 512, 4096, 256, 0);
}